// Round 13
// baseline (443.718 us; speedup 1.0000x reference)
//
#include <hip/hip_runtime.h>

typedef unsigned short ushort_t;
typedef unsigned int uint_t;
typedef __attribute__((ext_vector_type(8))) _Float16 f16x8;
typedef __attribute__((ext_vector_type(4))) float floatx4;

#define ZDIM 32
#define KDIM 4
#define HDIM 128
#define B_TOTAL 32768
#define TB 32

// ws layout (ushort element offsets): Wd fp16 [k][n][c], Wsm fp16 [m][n][c]
#define WS_WD16 0            // 4*1024*128 = 524288
#define WS_SM16 524288       // 3*128*128 = 49152

// LDS layout (byte offsets). D is fp16: [batch][i][j] at batch*1092 + i*34 + j
// (ushort units).
#define D_ROW   34
#define D_BP    1092
#define SH_D_OFF  0          // ushort[32][1092] = 69888 B
#define AUX_PITCH 132
#define SH_AUX_OFF 0         // float [3][32][132] = 50688 B (pre-loop, aliases D)
#define SH_H_OFF  50688      // half [32][136] = 8704 B (pre-loop, aliases D)
#define SH_Z_OFF  69888      // float [32][36] = 4608 B
#define SH_T_OFF  74496      // float [32][36] = 4608 B
#define LDS_BYTES 79104      // x2 = 158208 <= 160 KiB -> 2 WGs/CU via LDS

__device__ __forceinline__ float fast_tanh(float x) {
    float e = __expf(2.0f * x);
    return 1.0f - 2.0f / (e + 1.0f);
}
__device__ __forceinline__ float f16lo(uint_t v) {
    return (float)__builtin_bit_cast(_Float16, (ushort_t)(v & 0xFFFFu));
}
__device__ __forceinline__ float f16hi(uint_t v) {
    return (float)__builtin_bit_cast(_Float16, (ushort_t)(v >> 16));
}
__device__ __forceinline__ ushort_t f2h(float x) {
    return __builtin_bit_cast(ushort_t, (_Float16)x);
}
__device__ __forceinline__ ushort4 cvt4(float4 v) {
    ushort4 o; o.x = f2h(v.x); o.y = f2h(v.y); o.z = f2h(v.z); o.w = f2h(v.w);
    return o;
}
// pack 4 floats into 2 dwords of fp16 (kk folds at compile time under unroll)
__device__ __forceinline__ uint2 packq(float4 v) {
    uint2 r;
    r.x = (uint_t)f2h(v.x) | ((uint_t)f2h(v.y) << 16);
    r.y = (uint_t)f2h(v.z) | ((uint_t)f2h(v.w) << 16);
    return r;
}
__device__ __forceinline__ float half_at(uint2 q, int kk) {
    uint_t w = (kk & 2) ? q.y : q.x;
    return (kk & 1) ? f16hi(w) : f16lo(w);
}

// ---------------------------------------------------------------------------
// Kernel 1: convert Wd (reordered per-k-slice) and Wd1/Wd2/Wb to fp16.
// ---------------------------------------------------------------------------
__global__ __launch_bounds__(256) void convert_kernel(
    const float* __restrict__ Wd, const float* __restrict__ Wd1,
    const float* __restrict__ Wd2, const float* __restrict__ Wb,
    ushort_t* __restrict__ ws)
{
    int g = blockIdx.x * 256 + threadIdx.x;
    if (g < 131072) {
        int k = g >> 15;            // 32768 float4 per k-slice
        int rem = g & 32767;
        int n = rem >> 5;           // n = i*32+j
        int c4 = rem & 31;
        float4 v = *((const float4*)Wd + (size_t)(4 * n + k) * 32 + c4);
        ((ushort4*)(ws + WS_WD16))[g] = cvt4(v);
    } else {
        int s = g - 131072;         // [0, 12288)
        const float* src = (s < 4096) ? Wd1 : ((s < 8192) ? Wd2 : Wb);
        int r = s & 4095;
        float4 v = ((const float4*)src)[r];
        ((ushort4*)(ws + WS_SM16))[s] = cvt4(v);
    }
}

// ---------------------------------------------------------------------------
// Kernel 2: fused fp16 encoder GEMMs + K-step flow (round-8 structure).
// 512 threads, TB=32. __launch_bounds__(512, 3): empirical hipcc rule
// arch_cap = 256/min_waves -> ~85 arch regs. Rationale (rounds 8 vs 11/12):
//   r8  (512,4): 64 regs, 16 waves/CU, ~10-reg SPILL       -> 302 us
//   r11/12     : 128 regs, no spill, only 8 waves/CU       -> 188 us
// ~85 regs fits this kernel's ~70-75 peak demand (no spill) while LDS
// (79.1 KB x 2) still gives 2 WGs x 8 waves = 16 waves/CU.
// Each wave: one 16-batch row-half (rh=w&1) x 256-col group (cg=w>>1);
// the rh-pair reads the same B columns back-to-back (L1-resident).
// Flow: 16 threads/batch, j's {j2, j2+16}; mid-flow barrier per round-10.
// ---------------------------------------------------------------------------
__global__ __launch_bounds__(512, 3) void sylv_kernel(
    const ushort_t* __restrict__ wsb,
    const float* __restrict__ hglob,
    const float* __restrict__ z0,
    const float* __restrict__ bd,
    const float* __restrict__ bd1,
    const float* __restrict__ bd2,
    const float* __restrict__ bb,
    float* __restrict__ out)
{
    extern __shared__ char smem[];
    _Float16* Dh     = (_Float16*)(smem + SH_D_OFF);
    float*    sh_aux = (float*)(smem + SH_AUX_OFF);
    _Float16* sh_h   = (_Float16*)(smem + SH_H_OFF);
    float*    sh_z   = (float*)(smem + SH_Z_OFF);
    float*    sh_t   = (float*)(smem + SH_T_OFF);

    const int t   = threadIdx.x;
    const int bg0 = blockIdx.x * TB;
    const int lane = t & 63, w = t >> 6;
    const int l15 = lane & 15, l4 = lane >> 4;
    const int rh = w & 1;           // row-half (batches rh*16 .. rh*16+15)
    const int cg = w >> 1;          // column group (256 cols each)
    // flow mapping: 16 contiguous lanes (one quarter-wave) own one batch fb.
    const int j2 = t & 15;
    const int bq = (t >> 4) & 3;
    const int fb = (w & 1) | (bq << 1) | ((w >> 1) << 3);

    // ---- stage h (fp32 -> fp16 in LDS) and z0 ----
    {
        const float4* hsrc = (const float4*)(hglob + (size_t)bg0 * HDIM);
        #pragma unroll
        for (int it = 0; it < 2; ++it) {
            int c = t + it * 512;       // 1024 float4 chunks
            int row = c >> 5, col4 = c & 31;
            float4 v = hsrc[c];
            *(ushort4*)((ushort_t*)sh_h + row * 136 + col4 * 4) = cvt4(v);
        }
        int zb = t >> 4, zc = t & 15;
        float2 zv = *(const float2*)(z0 + (size_t)(bg0 + zb) * ZDIM + zc * 2);
        *(float2*)(sh_z + zb * 36 + zc * 2) = zv;
    }
    __syncthreads();

    // ---- A fragments for THIS wave's row-half: A[m=lane&15][k=quad*8+j] ----
    f16x8 ah[4];
    #pragma unroll
    for (int kc = 0; kc < 4; ++kc)
        ah[kc] = *(const f16x8*)(sh_h + (rh * 16 + l15) * 136 + kc * 32 + l4 * 8);

    // ---- small GEMMs (fp16): d1, d2, bpre -> aux[m][batch][n] ----
    // 24 p-jobs x 2 rh-waves = 48; each wave does 6 for its rh.
    #pragma unroll
    for (int pi = 0; pi < 6; ++pi) {
        int p = cg * 6 + pi;            // [0,24)
        int m_i = p >> 3, nt = p & 7, n = nt * 16 + l15;
        const _Float16* wp = (const _Float16*)(wsb + WS_SM16) + (size_t)(m_i * 128 + n) * 128 + l4 * 8;
        floatx4 a0 = {0.f, 0.f, 0.f, 0.f};
        #pragma unroll
        for (int kc = 0; kc < 4; ++kc) {
            f16x8 bh = *(const f16x8*)(wp + kc * 32);
            a0 = __builtin_amdgcn_mfma_f32_16x16x32_f16(ah[kc], bh, a0, 0, 0, 0);
        }
        const float* bv = (m_i == 0) ? bd1 : ((m_i == 1) ? bd2 : bb);
        float bias = bv[n];
        float* ap = sh_aux + m_i * (32 * AUX_PITCH) + n;
        #pragma unroll
        for (int r = 0; r < 4; ++r) {
            float v0 = a0[r] + bias;
            if (m_i < 2) v0 = fast_tanh(v0);
            ap[(rh * 16 + l4 * 4 + r) * AUX_PITCH] = v0;
        }
    }
    __syncthreads();

    // ---- aux -> 12 packed-fp16 dwords/thread, then free the D region ----
    uint2 d1a = packq(*(const float4*)(sh_aux + 0 * (32 * AUX_PITCH) + fb * AUX_PITCH + j2 * 4));
    uint2 d2a = packq(*(const float4*)(sh_aux + 1 * (32 * AUX_PITCH) + fb * AUX_PITCH + j2 * 4));
    uint2 bpa = packq(*(const float4*)(sh_aux + 2 * (32 * AUX_PITCH) + fb * AUX_PITCH + j2 * 4));
    uint2 d1b = packq(*(const float4*)(sh_aux + 0 * (32 * AUX_PITCH) + fb * AUX_PITCH + (j2 + 16) * 4));
    uint2 d2b = packq(*(const float4*)(sh_aux + 1 * (32 * AUX_PITCH) + fb * AUX_PITCH + (j2 + 16) * 4));
    uint2 bpb = packq(*(const float4*)(sh_aux + 2 * (32 * AUX_PITCH) + fb * AUX_PITCH + (j2 + 16) * 4));
    __syncthreads();

    float ld_acc = 0.f;
    const _Float16* Db  = Dh + fb * D_BP;

    #pragma unroll
    for (int kk = 0; kk < KDIM; ++kk) {
        // ---- GEMM: D_k[b][n] = h@Wd_k^T + bd (fp16 inputs, fp32 acc) ----
        const _Float16* wdk = (const _Float16*)(wsb + WS_WD16) + (size_t)kk * 131072;
        #pragma unroll
        for (int g = 0; g < 16; ++g) {
            int nc = cg * 256 + g * 16 + l15;
            const _Float16* w0 = wdk + (size_t)nc * 128 + l4 * 8;
            floatx4 a0 = {0.f,0.f,0.f,0.f};
            #pragma unroll
            for (int kc = 0; kc < 4; ++kc) {
                f16x8 b0 = *(const f16x8*)(w0 + kc * 32);
                a0 = __builtin_amdgcn_mfma_f32_16x16x32_f16(ah[kc], b0, a0, 0, 0, 0);
            }
            int ii = nc >> 5;
            int base = ii * D_ROW + (nc & 31);
            float bias0 = bd[4 * nc + kk];
            #pragma unroll
            for (int r = 0; r < 4; ++r)
                Dh[(rh * 16 + l4 * 4 + r) * D_BP + base] = (_Float16)(a0[r] + bias0);
        }
        __syncthreads();

        // ---- pre[j] = b[j] + z_per[j]*d2[j] + sum_{i>j} z_per[i]*D[i,j] ----
        const bool flip = (kk & 1) != 0;
        const int zj0 = flip ? (31 - j2) : j2;
        const int zj1 = flip ? (15 - j2) : (j2 + 16);
        float s0 = half_at(bpa, kk) + sh_z[fb * 36 + zj0] * half_at(d2a, kk);
        float s1 = half_at(bpb, kk) + sh_z[fb * 36 + zj1] * half_at(d2b, kk);
        #pragma unroll
        for (int i = 1; i <= 15; ++i) {       // masked vs j2
            float zi = sh_z[fb * 36 + (flip ? (31 - i) : i)];
            float dd = (float)Db[i * D_ROW + j2];
            s0 = fmaf(dd, (i > j2) ? zi : 0.f, s0);
        }
        #pragma unroll
        for (int i = 16; i < 32; ++i) {       // i > j2 always; s1 masked
            float zi = sh_z[fb * 36 + (flip ? (31 - i) : i)];
            s0 = fmaf((float)Db[i * D_ROW + j2], zi, s0);
            if (i >= 17)
                s1 = fmaf((float)Db[i * D_ROW + j2 + 16], (i > j2 + 16) ? zi : 0.f, s1);
        }
        float t0 = fast_tanh(s0), t1 = fast_tanh(s1);
        sh_t[fb * 36 + j2] = t0;
        sh_t[fb * 36 + j2 + 16] = t1;
        float dj0 = (1.f - t0 * t0) * (half_at(d1a, kk) * half_at(d2a, kk)) + 1.f;
        float dj1 = (1.f - t1 * t1) * (half_at(d1b, kk) * half_at(d2b, kk)) + 1.f;
        ld_acc += __logf(fabsf(dj0)) + __logf(fabsf(dj1));
        // barrier protects the sh_t hand-off (round-9 flake lesson)
        __syncthreads();

        // ---- dz[p] = t[p]*d1[p] + sum_{j>p} t[j]*D[p,j]; z update ----
        float dz0 = t0 * half_at(d1a, kk);    // p = j2
        float dz1 = t1 * half_at(d1b, kk);    // p = j2+16
        const uint_t* r0 = (const uint_t*)Db + j2 * 17;     // D_ROW/2 words
        const uint_t* r1 = (const uint_t*)Db + (j2 + 16) * 17;
        #pragma unroll
        for (int w2 = 0; w2 < 8; ++w2) {      // j in [0,16): only dz0, masked
            uint_t v = r0[w2];
            int j0 = 2 * w2;
            float tl = sh_t[fb * 36 + j0];
            float th = sh_t[fb * 36 + j0 + 1];
            dz0 = fmaf(f16lo(v), (j0 > j2) ? tl : 0.f, dz0);
            dz0 = fmaf(f16hi(v), (j0 + 1 > j2) ? th : 0.f, dz0);
        }
        #pragma unroll
        for (int w2 = 8; w2 < 16; ++w2) {     // j in [16,32): dz0 unmasked, dz1 masked
            uint_t v0 = r0[w2];
            uint_t v1 = r1[w2];
            int j0 = 2 * w2;
            float tl = sh_t[fb * 36 + j0];
            float th = sh_t[fb * 36 + j0 + 1];
            dz0 = fmaf(f16lo(v0), tl, dz0);
            dz0 = fmaf(f16hi(v0), th, dz0);
            dz1 = fmaf(f16lo(v1), (j0 > j2 + 16) ? tl : 0.f, dz1);
            dz1 = fmaf(f16hi(v1), (j0 + 1 > j2 + 16) ? th : 0.f, dz1);
        }
        sh_z[fb * 36 + zj0] += dz0;
        sh_z[fb * 36 + zj1] += dz1;
        __syncthreads();
    }

    // ---- epilogue: write z and log_det_j ----
    {
        int zb = t >> 4, zc = t & 15;
        float2 zv = *(const float2*)(sh_z + zb * 36 + zc * 2);
        *(float2*)(out + (size_t)(bg0 + zb) * ZDIM + zc * 2) = zv;
        float v = ld_acc;
        v += __shfl_xor(v, 1, 16);
        v += __shfl_xor(v, 2, 16);
        v += __shfl_xor(v, 4, 16);
        v += __shfl_xor(v, 8, 16);
        if (j2 == 0) out[(size_t)B_TOTAL * ZDIM + bg0 + fb] = v;
    }
}

extern "C" void kernel_launch(void* const* d_in, const int* in_sizes, int n_in,
                              void* d_out, int out_size, void* d_ws, size_t ws_size,
                              hipStream_t stream) {
    const float* z0  = (const float*)d_in[0];
    const float* h   = (const float*)d_in[1];
    const float* Wd  = (const float*)d_in[2];
    const float* bd  = (const float*)d_in[3];
    const float* Wd1 = (const float*)d_in[4];
    const float* bd1 = (const float*)d_in[5];
    const float* Wd2 = (const float*)d_in[6];
    const float* bd2 = (const float*)d_in[7];
    const float* Wb  = (const float*)d_in[8];
    const float* bb  = (const float*)d_in[9];
    ushort_t* ws = (ushort_t*)d_ws;
    float* out = (float*)d_out;

    convert_kernel<<<560, 256, 0, stream>>>(Wd, Wd1, Wd2, Wb, ws);

    (void)hipFuncSetAttribute((const void*)sylv_kernel,
                              hipFuncAttributeMaxDynamicSharedMemorySize, LDS_BYTES);
    sylv_kernel<<<B_TOTAL / TB, 512, LDS_BYTES, stream>>>(ws, h, z0, bd, bd1, bd2, bb, out);
}

// Round 14
// 378.801 us; speedup vs baseline: 1.1714x; 1.1714x over previous
//
#include <hip/hip_runtime.h>

typedef unsigned short ushort_t;
typedef unsigned int uint_t;
typedef __attribute__((ext_vector_type(8))) _Float16 f16x8;
typedef __attribute__((ext_vector_type(4))) float floatx4;

#define ZDIM 32
#define KDIM 4
#define HDIM 128
#define B_TOTAL 32768
#define TB 16

// ws layout (ushort element offsets): Wd fp16 [k][n][c], Wsm fp16 [m][n][c]
#define WS_WD16 0            // 4*1024*128 = 524288
#define WS_SM16 524288       // 3*128*128 = 49152

// LDS layout (byte offsets). D fp16: [batch][i][j] at batch*1096 + i*34 + j
// (ushort units).
#define D_ROW   34
#define D_BP    1096
#define SH_D_OFF  0          // ushort[16][1096] = 35072 B
#define AUX_PITCH 132
#define SH_AUX_OFF 0         // float [3][16][132] = 25344 B (pre-loop, aliases D)
#define SH_H_OFF  25344      // half [16][136] = 4352 B (pre-loop, aliases D; end 29696)
#define SH_Z_OFF  35072      // float [16][36] = 2304 B
#define SH_T_OFF  37376      // float [16][36] = 2304 B
#define LDS_BYTES 39680      // x4 = 158720 <= 160 KiB -> 4 WGs/CU

__device__ __forceinline__ float fast_tanh(float x) {
    float e = __expf(2.0f * x);
    return 1.0f - 2.0f / (e + 1.0f);
}
__device__ __forceinline__ float f16lo(uint_t v) {
    return (float)__builtin_bit_cast(_Float16, (ushort_t)(v & 0xFFFFu));
}
__device__ __forceinline__ float f16hi(uint_t v) {
    return (float)__builtin_bit_cast(_Float16, (ushort_t)(v >> 16));
}
__device__ __forceinline__ ushort_t f2h(float x) {
    return __builtin_bit_cast(ushort_t, (_Float16)x);
}
__device__ __forceinline__ ushort4 cvt4(float4 v) {
    ushort4 o; o.x = f2h(v.x); o.y = f2h(v.y); o.z = f2h(v.z); o.w = f2h(v.w);
    return o;
}
// pack 4 floats into 2 dwords of fp16 (kk folds at compile time under unroll)
__device__ __forceinline__ uint2 packq(float4 v) {
    uint2 r;
    r.x = (uint_t)f2h(v.x) | ((uint_t)f2h(v.y) << 16);
    r.y = (uint_t)f2h(v.z) | ((uint_t)f2h(v.w) << 16);
    return r;
}
__device__ __forceinline__ float half_at(uint2 q, int kk) {
    uint_t w = (kk & 2) ? q.y : q.x;
    return (kk & 1) ? f16hi(w) : f16lo(w);
}

// ---------------------------------------------------------------------------
// Kernel 1: convert Wd (reordered per-k-slice) and Wd1/Wd2/Wb to fp16.
// ---------------------------------------------------------------------------
__global__ __launch_bounds__(256) void convert_kernel(
    const float* __restrict__ Wd, const float* __restrict__ Wd1,
    const float* __restrict__ Wd2, const float* __restrict__ Wb,
    ushort_t* __restrict__ ws)
{
    int g = blockIdx.x * 256 + threadIdx.x;
    if (g < 131072) {
        int k = g >> 15;            // 32768 float4 per k-slice
        int rem = g & 32767;
        int n = rem >> 5;           // n = i*32+j
        int c4 = rem & 31;
        float4 v = *((const float4*)Wd + (size_t)(4 * n + k) * 32 + c4);
        ((ushort4*)(ws + WS_WD16))[g] = cvt4(v);
    } else {
        int s = g - 131072;         // [0, 12288)
        const float* src = (s < 4096) ? Wd1 : ((s < 8192) ? Wd2 : Wb);
        int r = s & 4095;
        float4 v = ((const float4*)src)[r];
        ((ushort4*)(ws + WS_SM16))[s] = cvt4(v);
    }
}

// ---------------------------------------------------------------------------
// Kernel 2: fused fp16 encoder GEMMs + K-step flow. TB=16 batches/WG,
// 256 threads (4 waves), __launch_bounds__(256,2) -> 128 arch regs.
// Occupancy model (post r13): at 128 regs a wave needs ~136 unified regs ->
// 3 waves/SIMD; LDS is the binding constraint we control. TB=16 shrinks
// LDS to 39.7 KB -> 4 WGs/CU = 16 waves (vs 8 in r11/12), AND the per-wave
// A-fragment state halves (one 16-row tile covers all 16 batches, ~70-reg
// demand -> no spill at the 128 cap). Cost: 2048 WGs x 1 MB Wd = 2 GB L2
// (~58 us aggregate), overlapped across 16 waves/CU.
// Flow: 16 threads/batch (fb = t>>4), j's {j2, j2+16}; mid-flow barrier.
// ---------------------------------------------------------------------------
__global__ __launch_bounds__(256, 2) void sylv_kernel(
    const ushort_t* __restrict__ wsb,
    const float* __restrict__ hglob,
    const float* __restrict__ z0,
    const float* __restrict__ bd,
    const float* __restrict__ bd1,
    const float* __restrict__ bd2,
    const float* __restrict__ bb,
    float* __restrict__ out)
{
    extern __shared__ char smem[];
    _Float16* Dh     = (_Float16*)(smem + SH_D_OFF);
    float*    sh_aux = (float*)(smem + SH_AUX_OFF);
    _Float16* sh_h   = (_Float16*)(smem + SH_H_OFF);
    float*    sh_z   = (float*)(smem + SH_Z_OFF);
    float*    sh_t   = (float*)(smem + SH_T_OFF);

    const int t   = threadIdx.x;
    const int bg0 = blockIdx.x * TB;
    const int lane = t & 63, w = t >> 6;    // w = 0..3 = column group
    const int l15 = lane & 15, l4 = lane >> 4;
    // flow mapping: 16 contiguous threads own one batch fb.
    const int j2 = t & 15;
    const int fb = t >> 4;          // 0..15

    // ---- stage h (fp32 -> fp16 in LDS) and z0 ----
    {
        const float4* hsrc = (const float4*)(hglob + (size_t)bg0 * HDIM);
        #pragma unroll
        for (int it = 0; it < 2; ++it) {
            int c = t + it * 256;       // 512 float4 chunks
            int row = c >> 5, col4 = c & 31;
            float4 v = hsrc[c];
            *(ushort4*)((ushort_t*)sh_h + row * 136 + col4 * 4) = cvt4(v);
        }
        float2 zv = *(const float2*)(z0 + (size_t)(bg0 + fb) * ZDIM + j2 * 2);
        *(float2*)(sh_z + fb * 36 + j2 * 2) = zv;
    }
    __syncthreads();

    // ---- A fragments: ONE 16-row tile (all TB=16 batches), all waves ----
    f16x8 ah[4];
    #pragma unroll
    for (int kc = 0; kc < 4; ++kc)
        ah[kc] = *(const f16x8*)(sh_h + l15 * 136 + kc * 32 + l4 * 8);

    // ---- small GEMMs (fp16): d1, d2, bpre -> aux[m][batch][n] ----
    // 24 (m,ntile) jobs over 4 waves: 6 per wave.
    #pragma unroll
    for (int pi = 0; pi < 6; ++pi) {
        int p = w * 6 + pi;             // [0,24)
        int m_i = p >> 3, nt = p & 7, n = nt * 16 + l15;
        const _Float16* wp = (const _Float16*)(wsb + WS_SM16) + (size_t)(m_i * 128 + n) * 128 + l4 * 8;
        floatx4 a0 = {0.f, 0.f, 0.f, 0.f};
        #pragma unroll
        for (int kc = 0; kc < 4; ++kc) {
            f16x8 bh = *(const f16x8*)(wp + kc * 32);
            a0 = __builtin_amdgcn_mfma_f32_16x16x32_f16(ah[kc], bh, a0, 0, 0, 0);
        }
        const float* bv = (m_i == 0) ? bd1 : ((m_i == 1) ? bd2 : bb);
        float bias = bv[n];
        float* ap = sh_aux + m_i * (TB * AUX_PITCH) + n;
        #pragma unroll
        for (int r = 0; r < 4; ++r) {
            float v0 = a0[r] + bias;
            if (m_i < 2) v0 = fast_tanh(v0);
            ap[(l4 * 4 + r) * AUX_PITCH] = v0;
        }
    }
    __syncthreads();

    // ---- aux -> 12 packed-fp16 dwords/thread, then free the D region ----
    uint2 d1a = packq(*(const float4*)(sh_aux + 0 * (TB * AUX_PITCH) + fb * AUX_PITCH + j2 * 4));
    uint2 d2a = packq(*(const float4*)(sh_aux + 1 * (TB * AUX_PITCH) + fb * AUX_PITCH + j2 * 4));
    uint2 bpa = packq(*(const float4*)(sh_aux + 2 * (TB * AUX_PITCH) + fb * AUX_PITCH + j2 * 4));
    uint2 d1b = packq(*(const float4*)(sh_aux + 0 * (TB * AUX_PITCH) + fb * AUX_PITCH + (j2 + 16) * 4));
    uint2 d2b = packq(*(const float4*)(sh_aux + 1 * (TB * AUX_PITCH) + fb * AUX_PITCH + (j2 + 16) * 4));
    uint2 bpb = packq(*(const float4*)(sh_aux + 2 * (TB * AUX_PITCH) + fb * AUX_PITCH + (j2 + 16) * 4));
    __syncthreads();

    float ld_acc = 0.f;
    const _Float16* Db  = Dh + fb * D_BP;

    #pragma unroll
    for (int kk = 0; kk < KDIM; ++kk) {
        // ---- GEMM: D_k[b][n] = h@Wd_k^T + bd (fp16 inputs, fp32 acc) ----
        const _Float16* wdk = (const _Float16*)(wsb + WS_WD16) + (size_t)kk * 131072;
        #pragma unroll
        for (int g = 0; g < 16; ++g) {
            int nc = w * 256 + g * 16 + l15;
            const _Float16* w0 = wdk + (size_t)nc * 128 + l4 * 8;
            floatx4 a0 = {0.f,0.f,0.f,0.f};
            #pragma unroll
            for (int kc = 0; kc < 4; ++kc) {
                f16x8 b0 = *(const f16x8*)(w0 + kc * 32);
                a0 = __builtin_amdgcn_mfma_f32_16x16x32_f16(ah[kc], b0, a0, 0, 0, 0);
            }
            int ii = nc >> 5;
            int base = ii * D_ROW + (nc & 31);
            float bias0 = bd[4 * nc + kk];
            #pragma unroll
            for (int r = 0; r < 4; ++r)
                Dh[(l4 * 4 + r) * D_BP + base] = (_Float16)(a0[r] + bias0);
        }
        __syncthreads();

        // ---- pre[j] = b[j] + z_per[j]*d2[j] + sum_{i>j} z_per[i]*D[i,j] ----
        const bool flip = (kk & 1) != 0;
        const int zj0 = flip ? (31 - j2) : j2;
        const int zj1 = flip ? (15 - j2) : (j2 + 16);
        float s0 = half_at(bpa, kk) + sh_z[fb * 36 + zj0] * half_at(d2a, kk);
        float s1 = half_at(bpb, kk) + sh_z[fb * 36 + zj1] * half_at(d2b, kk);
        #pragma unroll
        for (int i = 1; i <= 15; ++i) {       // masked vs j2
            float zi = sh_z[fb * 36 + (flip ? (31 - i) : i)];
            float dd = (float)Db[i * D_ROW + j2];
            s0 = fmaf(dd, (i > j2) ? zi : 0.f, s0);
        }
        #pragma unroll
        for (int i = 16; i < 32; ++i) {       // i > j2 always; s1 masked
            float zi = sh_z[fb * 36 + (flip ? (31 - i) : i)];
            s0 = fmaf((float)Db[i * D_ROW + j2], zi, s0);
            if (i >= 17)
                s1 = fmaf((float)Db[i * D_ROW + j2 + 16], (i > j2 + 16) ? zi : 0.f, s1);
        }
        float t0 = fast_tanh(s0), t1 = fast_tanh(s1);
        sh_t[fb * 36 + j2] = t0;
        sh_t[fb * 36 + j2 + 16] = t1;
        float dj0 = (1.f - t0 * t0) * (half_at(d1a, kk) * half_at(d2a, kk)) + 1.f;
        float dj1 = (1.f - t1 * t1) * (half_at(d1b, kk) * half_at(d2b, kk)) + 1.f;
        ld_acc += __logf(fabsf(dj0)) + __logf(fabsf(dj1));
        // barrier protects the sh_t hand-off (round-9 flake lesson)
        __syncthreads();

        // ---- dz[p] = t[p]*d1[p] + sum_{j>p} t[j]*D[p,j]; z update ----
        float dz0 = t0 * half_at(d1a, kk);    // p = j2
        float dz1 = t1 * half_at(d1b, kk);    // p = j2+16
        const uint_t* r0 = (const uint_t*)Db + j2 * 17;     // D_ROW/2 words
        const uint_t* r1 = (const uint_t*)Db + (j2 + 16) * 17;
        #pragma unroll
        for (int w2 = 0; w2 < 8; ++w2) {      // j in [0,16): only dz0, masked
            uint_t v = r0[w2];
            int j0 = 2 * w2;
            float tl = sh_t[fb * 36 + j0];
            float th = sh_t[fb * 36 + j0 + 1];
            dz0 = fmaf(f16lo(v), (j0 > j2) ? tl : 0.f, dz0);
            dz0 = fmaf(f16hi(v), (j0 + 1 > j2) ? th : 0.f, dz0);
        }
        #pragma unroll
        for (int w2 = 8; w2 < 16; ++w2) {     // j in [16,32): dz0 unmasked, dz1 masked
            uint_t v0 = r0[w2];
            uint_t v1 = r1[w2];
            int j0 = 2 * w2;
            float tl = sh_t[fb * 36 + j0];
            float th = sh_t[fb * 36 + j0 + 1];
            dz0 = fmaf(f16lo(v0), tl, dz0);
            dz0 = fmaf(f16hi(v0), th, dz0);
            dz1 = fmaf(f16lo(v1), (j0 > j2 + 16) ? tl : 0.f, dz1);
            dz1 = fmaf(f16hi(v1), (j0 + 1 > j2 + 16) ? th : 0.f, dz1);
        }
        sh_z[fb * 36 + zj0] += dz0;
        sh_z[fb * 36 + zj1] += dz1;
        __syncthreads();
    }

    // ---- epilogue: write z and log_det_j ----
    {
        float2 zv = *(const float2*)(sh_z + fb * 36 + j2 * 2);
        *(float2*)(out + (size_t)(bg0 + fb) * ZDIM + j2 * 2) = zv;
        float v = ld_acc;
        v += __shfl_xor(v, 1, 16);
        v += __shfl_xor(v, 2, 16);
        v += __shfl_xor(v, 4, 16);
        v += __shfl_xor(v, 8, 16);
        if (j2 == 0) out[(size_t)B_TOTAL * ZDIM + bg0 + fb] = v;
    }
}

extern "C" void kernel_launch(void* const* d_in, const int* in_sizes, int n_in,
                              void* d_out, int out_size, void* d_ws, size_t ws_size,
                              hipStream_t stream) {
    const float* z0  = (const float*)d_in[0];
    const float* h   = (const float*)d_in[1];
    const float* Wd  = (const float*)d_in[2];
    const float* bd  = (const float*)d_in[3];
    const float* Wd1 = (const float*)d_in[4];
    const float* bd1 = (const float*)d_in[5];
    const float* Wd2 = (const float*)d_in[6];
    const float* bd2 = (const float*)d_in[7];
    const float* Wb  = (const float*)d_in[8];
    const float* bb  = (const float*)d_in[9];
    ushort_t* ws = (ushort_t*)d_ws;
    float* out = (float*)d_out;

    convert_kernel<<<560, 256, 0, stream>>>(Wd, Wd1, Wd2, Wb, ws);

    (void)hipFuncSetAttribute((const void*)sylv_kernel,
                              hipFuncAttributeMaxDynamicSharedMemorySize, LDS_BYTES);
    sylv_kernel<<<B_TOTAL / TB, 256, LDS_BYTES, stream>>>(ws, h, z0, bd, bd1, bd2, bb, out);
}